// Round 2
// baseline (9108.873 us; speedup 1.0000x reference)
//
#include <hip/hip_runtime.h>
#include <hip/hip_bf16.h>

#define NN 200000
#define NE 3200000
#define NG 4096
#define INC 78
#define C1 64
#define C2 128
#define ODIM 128

using bf16 = __hip_bfloat16;

static inline size_t alignup(size_t x) { return (x + 255) & ~size_t(255); }

__device__ __forceinline__ float bf2f(unsigned short u) {
    return __uint_as_float(((unsigned)u) << 16);
}

// ---- deg[dst[e]] += 1 ----
__global__ void deg_kernel(const int* __restrict__ dst, float* __restrict__ deg) {
    int e = blockIdx.x * 256 + threadIdx.x;
    if (e < NE) atomicAdd(&deg[dst[e]], 1.0f);
}

// ---- dinv[n] = rsqrt(deg[n] + 1) ----
__global__ void dinv_kernel(float* __restrict__ deg) {
    int n = blockIdx.x * 256 + threadIdx.x;
    if (n < NN) deg[n] = rsqrtf(deg[n] + 1.0f);
}

// ---- wn[e] = dinv[src]*dinv[dst] ----
__global__ void wnorm_kernel(const int* __restrict__ src, const int* __restrict__ dst,
                             const float* __restrict__ dinv, float* __restrict__ wn) {
    int e = blockIdx.x * 256 + threadIdx.x;
    if (e < NE) wn[e] = dinv[src[e]] * dinv[dst[e]];
}

// ---- cnt[batch[n]] += 1 ----
__global__ void count_kernel(const int* __restrict__ batch, float* __restrict__ cnt) {
    int n = blockIdx.x * 256 + threadIdx.x;
    if (n < NN) atomicAdd(&cnt[batch[n]], 1.0f);
}

// ---- hw_c = (x @ W1[:, c0:c0+CH]) as bf16 ----
template <int CH>
__global__ void gemm1_kernel(const float* __restrict__ x, const float* __restrict__ W,
                             int c0, bf16* __restrict__ out) {
    __shared__ float Ws[INC * CH];
    for (int i = threadIdx.x; i < INC * CH; i += 256) {
        int k = i / CH, j = i % CH;
        Ws[i] = W[k * C1 + c0 + j];
    }
    __syncthreads();
    constexpr int NPB = 256 / CH;
    int node = blockIdx.x * NPB + threadIdx.x / CH;
    int j = threadIdx.x % CH;
    const float* xr = x + (size_t)node * INC;
    float acc = 0.f;
    #pragma unroll
    for (int k = 0; k < INC; ++k) acc += xr[k] * Ws[k * CH + j];
    out[(size_t)node * CH + j] = __float2bfloat16(acc);
}

// ---- hw_c = (h1 @ W2[:, c0:c0+CH]) as bf16 ----
template <int CH>
__global__ void gemm2_kernel(const bf16* __restrict__ h, const float* __restrict__ W,
                             int c0, bf16* __restrict__ out) {
    __shared__ float Ws[C1 * CH];
    for (int i = threadIdx.x; i < C1 * CH; i += 256) {
        int k = i / CH, j = i % CH;
        Ws[i] = W[k * C2 + c0 + j];
    }
    __syncthreads();
    constexpr int NPB = 256 / CH;
    int node = blockIdx.x * NPB + threadIdx.x / CH;
    int j = threadIdx.x % CH;
    const unsigned short* hr = (const unsigned short*)(h + (size_t)node * C1);
    float acc = 0.f;
    #pragma unroll
    for (int k = 0; k < C1; ++k) acc += bf2f(hr[k]) * Ws[k * CH + j];
    out[(size_t)node * CH + j] = __float2bfloat16(acc);
}

// ---- agg[n,j] = hw[n,j]*dinv[n]^2 (self loop) ----
template <int CH>
__global__ void init_agg_kernel(const bf16* __restrict__ hw, const float* __restrict__ dinv,
                                float* __restrict__ agg) {
    int idx = blockIdx.x * 256 + threadIdx.x;
    if (idx < NN * CH) {
        int n = idx / CH;
        float d = dinv[n];
        agg[idx] = bf2f(((const unsigned short*)hw)[idx]) * d * d;
    }
}

// ---- agg[dst, j4..j4+3] += hw[src, j4..j4+3]*wn[e] ----
template <int CH>
__global__ void scatter_kernel(const int* __restrict__ src, const int* __restrict__ dst,
                               const float* __restrict__ wn, const bf16* __restrict__ hw,
                               float* __restrict__ agg) {
    constexpr int JG = CH / 4;
    size_t gid = (size_t)blockIdx.x * 256 + threadIdx.x;
    if (gid >= (size_t)NE * JG) return;
    int e = (int)(gid / JG);
    int j4 = (int)(gid % JG) * 4;
    int s = src[e], d = dst[e];
    float w = wn[e];
    ushort4 raw = *reinterpret_cast<const ushort4*>((const unsigned short*)hw + (size_t)s * CH + j4);
    float* base = agg + (size_t)d * CH + j4;
    atomicAdd(base + 0, bf2f(raw.x) * w);
    atomicAdd(base + 1, bf2f(raw.y) * w);
    atomicAdd(base + 2, bf2f(raw.z) * w);
    atomicAdd(base + 3, bf2f(raw.w) * w);
}

// ---- h1[n, c0+j] = bf16(relu(agg[n,j] + b1[c0+j])) ----
template <int CH>
__global__ void bias_relu_h1_kernel(const float* __restrict__ agg, const float* __restrict__ b,
                                    int c0, bf16* __restrict__ h1) {
    int idx = blockIdx.x * 256 + threadIdx.x;
    if (idx < NN * CH) {
        int n = idx / CH, j = idx % CH;
        float v = fmaxf(agg[idx] + b[c0 + j], 0.f);
        h1[(size_t)n * C1 + c0 + j] = __float2bfloat16(v);
    }
}

// ---- pooled[batch[n], c0+j] += relu(agg[n,j] + b2[c0+j]) ----
template <int CH>
__global__ void relu_pool_kernel(const float* __restrict__ agg, const float* __restrict__ b,
                                 int c0, const int* __restrict__ batch,
                                 float* __restrict__ pooled) {
    int idx = blockIdx.x * 256 + threadIdx.x;
    if (idx < NN * CH) {
        int n = idx / CH, j = idx % CH;
        float v = fmaxf(agg[idx] + b[c0 + j], 0.f);
        atomicAdd(&pooled[(size_t)batch[n] * C2 + c0 + j], v);
    }
}

// ---- out = (pooled / max(cnt,1)) @ fc_w + fc_b ----
__global__ void final_kernel(const float* __restrict__ pooled, const float* __restrict__ cnt,
                             const float* __restrict__ fcw, const float* __restrict__ fcb,
                             float* __restrict__ out) {
    int idx = blockIdx.x * 256 + threadIdx.x;
    if (idx < NG * ODIM) {
        int g = idx >> 7;
        int o = idx & 127;
        float inv = 1.0f / fmaxf(cnt[g], 1.0f);
        float acc = fcb[o];
        const float* pr = pooled + (size_t)g * C2;
        #pragma unroll
        for (int k = 0; k < C2; ++k) acc += pr[k] * inv * fcw[k * ODIM + o];
        out[idx] = acc;
    }
}

static size_t need_bytes(int CH) {
    size_t s = 0;
    s += alignup((size_t)NN * 4);        // dinv
    s += alignup((size_t)NE * 4);        // wnorm
    s += alignup((size_t)NN * C1 * 2);   // h1 bf16
    s += alignup((size_t)NG * C2 * 4);   // pooled
    s += alignup((size_t)NG * 4);        // cnt
    s += alignup((size_t)NN * CH * 2);   // hw chunk bf16
    s += alignup((size_t)NN * CH * 4);   // agg chunk f32
    return s;
}

template <int CH>
static void run_pipeline(const float* x, const int* src, const int* dst, const int* bat,
                         const float* W1, const float* b1, const float* W2, const float* b2,
                         const float* fcw, const float* fcb, float* out,
                         char* ws, hipStream_t stream) {
    constexpr int CH1 = (CH < C1) ? CH : C1;
    constexpr int CH2 = CH;

    float* dinv   = (float*)ws; ws += alignup((size_t)NN * 4);
    float* wn     = (float*)ws; ws += alignup((size_t)NE * 4);
    bf16*  h1     = (bf16*)ws;  ws += alignup((size_t)NN * C1 * 2);
    float* pooled = (float*)ws; ws += alignup((size_t)NG * C2 * 4);
    float* cnt    = (float*)ws; ws += alignup((size_t)NG * 4);
    bf16*  hwc    = (bf16*)ws;  ws += alignup((size_t)NN * CH * 2);
    float* aggc   = (float*)ws; ws += alignup((size_t)NN * CH * 4);

    hipMemsetAsync(dinv, 0, (size_t)NN * 4, stream);
    hipMemsetAsync(pooled, 0, (size_t)NG * C2 * 4, stream);
    hipMemsetAsync(cnt, 0, (size_t)NG * 4, stream);

    deg_kernel<<<(NE + 255) / 256, 256, 0, stream>>>(dst, dinv);
    dinv_kernel<<<(NN + 255) / 256, 256, 0, stream>>>(dinv);
    wnorm_kernel<<<(NE + 255) / 256, 256, 0, stream>>>(src, dst, dinv, wn);
    count_kernel<<<(NN + 255) / 256, 256, 0, stream>>>(bat, cnt);

    for (int c0 = 0; c0 < C1; c0 += CH1) {
        gemm1_kernel<CH1><<<NN / (256 / CH1), 256, 0, stream>>>(x, W1, c0, hwc);
        init_agg_kernel<CH1><<<(NN * CH1 + 255) / 256, 256, 0, stream>>>(hwc, dinv, aggc);
        scatter_kernel<CH1><<<(unsigned)(((size_t)NE * (CH1 / 4) + 255) / 256), 256, 0, stream>>>(
            src, dst, wn, hwc, aggc);
        bias_relu_h1_kernel<CH1><<<(NN * CH1 + 255) / 256, 256, 0, stream>>>(aggc, b1, c0, h1);
    }

    for (int c0 = 0; c0 < C2; c0 += CH2) {
        gemm2_kernel<CH2><<<NN / (256 / CH2), 256, 0, stream>>>(h1, W2, c0, hwc);
        init_agg_kernel<CH2><<<(NN * CH2 + 255) / 256, 256, 0, stream>>>(hwc, dinv, aggc);
        scatter_kernel<CH2><<<(unsigned)(((size_t)NE * (CH2 / 4) + 255) / 256), 256, 0, stream>>>(
            src, dst, wn, hwc, aggc);
        relu_pool_kernel<CH2><<<(NN * CH2 + 255) / 256, 256, 0, stream>>>(aggc, b2, c0, bat, pooled);
    }

    final_kernel<<<(NG * ODIM + 255) / 256, 256, 0, stream>>>(pooled, cnt, fcw, fcb, out);
}

extern "C" void kernel_launch(void* const* d_in, const int* in_sizes, int n_in,
                              void* d_out, int out_size, void* d_ws, size_t ws_size,
                              hipStream_t stream) {
    const float* x   = (const float*)d_in[0];
    const int*   ei  = (const int*)d_in[1];
    const int*   bat = (const int*)d_in[2];
    const float* W1  = (const float*)d_in[3];
    const float* b1  = (const float*)d_in[4];
    const float* W2  = (const float*)d_in[5];
    const float* b2  = (const float*)d_in[6];
    const float* fcw = (const float*)d_in[7];
    const float* fcb = (const float*)d_in[8];
    float* out = (float*)d_out;

    const int* src = ei;        // edge_index[0]
    const int* dst = ei + NE;   // edge_index[1]
    char* ws = (char*)d_ws;

    if (ws_size >= need_bytes(128))
        run_pipeline<128>(x, src, dst, bat, W1, b1, W2, b2, fcw, fcb, out, ws, stream);
    else if (ws_size >= need_bytes(64))
        run_pipeline<64>(x, src, dst, bat, W1, b1, W2, b2, fcw, fcb, out, ws, stream);
    else if (ws_size >= need_bytes(32))
        run_pipeline<32>(x, src, dst, bat, W1, b1, W2, b2, fcw, fcb, out, ws, stream);
    else if (ws_size >= need_bytes(16))
        run_pipeline<16>(x, src, dst, bat, W1, b1, W2, b2, fcw, fcb, out, ws, stream);
    else
        run_pipeline<8>(x, src, dst, bat, W1, b1, W2, b2, fcw, fcb, out, ws, stream);
}

// Round 3
// 1342.681 us; speedup vs baseline: 6.7841x; 6.7841x over previous
//
#include <hip/hip_runtime.h>
#include <hip/hip_bf16.h>

#define NN 200000
#define NE 3200000
#define NG 4096
#define INC 78
#define C1 64
#define C2 128
#define ODIM 128

using bf16 = __hip_bfloat16;

static inline size_t alignup(size_t x) { return (x + 255) & ~size_t(255); }

__device__ __forceinline__ float bf2f(unsigned short u) {
    return __uint_as_float(((unsigned)u) << 16);
}

// ---- count[dst[e]] += 1 (in-degree, no self loop) ----
__global__ void hist_kernel(const int* __restrict__ dst, int* __restrict__ count) {
    int e = blockIdx.x * 256 + threadIdx.x;
    if (e < NE) atomicAdd(&count[dst[e]], 1);
}

// ---- dinv[n] = rsqrt(count[n] + 1) ----
__global__ void dinv_kernel(const int* __restrict__ count, float* __restrict__ dinv) {
    int n = blockIdx.x * 256 + threadIdx.x;
    if (n < NN) dinv[n] = rsqrtf((float)count[n] + 1.0f);
}

// ---- exclusive scan, 3-kernel: per-block, block-sums, add ----
__global__ void scan_block_kernel(const int* __restrict__ in, int* __restrict__ out,
                                  int* __restrict__ bsum) {
    __shared__ int tmp[256];
    int tid = threadIdx.x, gid = blockIdx.x * 256 + tid;
    int v = (gid < NN) ? in[gid] : 0;
    tmp[tid] = v;
    __syncthreads();
    for (int off = 1; off < 256; off <<= 1) {
        int t = (tid >= off) ? tmp[tid - off] : 0;
        __syncthreads();
        tmp[tid] += t;
        __syncthreads();
    }
    if (gid < NN) out[gid] = tmp[tid] - v;  // exclusive
    if (tid == 255) bsum[blockIdx.x] = tmp[255];
}

__global__ void scan_bsum_kernel(int* __restrict__ bsum, int nb) {
    __shared__ int tmp[1024];
    int tid = threadIdx.x;
    int v = (tid < nb) ? bsum[tid] : 0;
    tmp[tid] = v;
    __syncthreads();
    for (int off = 1; off < 1024; off <<= 1) {
        int t = (tid >= off) ? tmp[tid - off] : 0;
        __syncthreads();
        tmp[tid] += t;
        __syncthreads();
    }
    if (tid < nb) bsum[tid] = tmp[tid] - v;  // exclusive
}

__global__ void scan_add_kernel(int* __restrict__ rs, const int* __restrict__ bsum) {
    int gid = blockIdx.x * 256 + threadIdx.x;
    if (gid < NN) rs[gid] += bsum[blockIdx.x];
    if (gid == 0) rs[NN] = NE;
}

__global__ void copy_int_kernel(const int* __restrict__ a, int* __restrict__ b) {
    int i = blockIdx.x * 256 + threadIdx.x;
    if (i < NN) b[i] = a[i];
}

// ---- fill CSR: colval[pos] = {src, bits(dinv[src])} ----
__global__ void build_csr_kernel(const int* __restrict__ src, const int* __restrict__ dst,
                                 const float* __restrict__ dinv, int* __restrict__ cursor,
                                 int2* __restrict__ colval) {
    int e = blockIdx.x * 256 + threadIdx.x;
    if (e < NE) {
        int s = src[e], d = dst[e];
        int pos = atomicAdd(&cursor[d], 1);
        int2 cv;
        cv.x = s;
        cv.y = __float_as_int(dinv[s]);
        colval[pos] = cv;
    }
}

// ---- cnt[batch[n]] += 1 ----
__global__ void count_kernel(const int* __restrict__ batch, float* __restrict__ cnt) {
    int n = blockIdx.x * 256 + threadIdx.x;
    if (n < NN) atomicAdd(&cnt[batch[n]], 1.0f);
}

// ---- hw1 = bf16(x @ W1), full 64 ch ----
__global__ void gemm1_kernel(const float* __restrict__ x, const float* __restrict__ W,
                             bf16* __restrict__ out) {
    __shared__ float Ws[INC * C1];
    for (int i = threadIdx.x; i < INC * C1; i += 256) Ws[i] = W[i];
    __syncthreads();
    int node = blockIdx.x * 4 + (threadIdx.x >> 6);
    int c = threadIdx.x & 63;
    const float* xr = x + (size_t)node * INC;
    float acc = 0.f;
    #pragma unroll
    for (int k = 0; k < INC; ++k) acc += xr[k] * Ws[k * C1 + c];
    out[(size_t)node * C1 + c] = __float2bfloat16(acc);
}

// ---- hw2 chunk = bf16(h1 @ W2[:, c0:c0+CH]) ----
template <int CH>
__global__ void gemm2_kernel(const bf16* __restrict__ h, const float* __restrict__ W,
                             int c0, bf16* __restrict__ out) {
    __shared__ float Ws[C1 * CH];
    for (int i = threadIdx.x; i < C1 * CH; i += 256) {
        int k = i / CH, j = i % CH;
        Ws[i] = W[k * C2 + c0 + j];
    }
    __syncthreads();
    constexpr int NPB = 256 / CH;
    int node = blockIdx.x * NPB + threadIdx.x / CH;
    int j = threadIdx.x % CH;
    const unsigned short* hr = (const unsigned short*)(h + (size_t)node * C1);
    float acc = 0.f;
    #pragma unroll
    for (int k = 0; k < C1; ++k) acc += bf2f(hr[k]) * Ws[k * CH + j];
    out[(size_t)node * CH + j] = __float2bfloat16(acc);
}

// ---- register-accumulated neighbor sum: sum over incoming edges of hw[src,c]*dinv[src] ----
template <int C>
__device__ __forceinline__ float agg_edges(const int2* __restrict__ cv, int start, int len,
                                           const unsigned short* __restrict__ hw, int c) {
    float acc = 0.f;
    int e = 0;
    for (; e + 4 <= len; e += 4) {
        int2 a = cv[start + e + 0];
        int2 b = cv[start + e + 1];
        int2 c2 = cv[start + e + 2];
        int2 d = cv[start + e + 3];
        float va = bf2f(hw[(size_t)a.x * C + c]);
        float vb = bf2f(hw[(size_t)b.x * C + c]);
        float vc = bf2f(hw[(size_t)c2.x * C + c]);
        float vd = bf2f(hw[(size_t)d.x * C + c]);
        acc += va * __int_as_float(a.y) + vb * __int_as_float(b.y) +
               vc * __int_as_float(c2.y) + vd * __int_as_float(d.y);
    }
    for (; e < len; ++e) {
        int2 a = cv[start + e];
        acc += bf2f(hw[(size_t)a.x * C + c]) * __int_as_float(a.y);
    }
    return acc;
}

// ---- layer1 aggregate + self loop + bias + relu -> h1 bf16 (wave per node, no atomics) ----
__global__ void agg1_kernel(const int2* __restrict__ cv, const int* __restrict__ rs,
                            const float* __restrict__ dinv, const unsigned short* __restrict__ hw1,
                            const float* __restrict__ b1, bf16* __restrict__ h1) {
    int node = blockIdx.x * 4 + (threadIdx.x >> 6);
    if (node >= NN) return;
    int c = threadIdx.x & 63;
    int start = rs[node], len = rs[node + 1] - start;
    float acc = agg_edges<C1>(cv, start, len, hw1, c);
    float dn = dinv[node];
    acc = dn * (acc + bf2f(hw1[(size_t)node * C1 + c]) * dn);
    float h = fmaxf(acc + b1[c], 0.f);
    h1[(size_t)node * C1 + c] = __float2bfloat16(h);
}

// ---- layer2 aggregate + self loop + bias + relu + pooled atomicAdd ----
template <int CH>
__global__ void agg2_kernel(const int2* __restrict__ cv, const int* __restrict__ rs,
                            const float* __restrict__ dinv, const unsigned short* __restrict__ hw,
                            const float* __restrict__ b2, int c0, const int* __restrict__ batch,
                            float* __restrict__ pooled) {
    constexpr int NPB = 256 / CH;
    int node = blockIdx.x * NPB + threadIdx.x / CH;
    if (node >= NN) return;
    int j = threadIdx.x % CH;
    int start = rs[node], len = rs[node + 1] - start;
    float acc = agg_edges<CH>(cv, start, len, hw, j);
    float dn = dinv[node];
    acc = dn * (acc + bf2f(hw[(size_t)node * CH + j]) * dn);
    float v = fmaxf(acc + b2[c0 + j], 0.f);
    atomicAdd(&pooled[(size_t)batch[node] * C2 + c0 + j], v);
}

// ---- out = (pooled / max(cnt,1)) @ fc_w + fc_b ----
__global__ void final_kernel(const float* __restrict__ pooled, const float* __restrict__ cnt,
                             const float* __restrict__ fcw, const float* __restrict__ fcb,
                             float* __restrict__ out) {
    int idx = blockIdx.x * 256 + threadIdx.x;
    if (idx < NG * ODIM) {
        int g = idx >> 7;
        int o = idx & 127;
        float inv = 1.0f / fmaxf(cnt[g], 1.0f);
        float acc = fcb[o];
        const float* pr = pooled + (size_t)g * C2;
        #pragma unroll
        for (int k = 0; k < C2; ++k) acc += pr[k] * inv * fcw[k * ODIM + o];
        out[idx] = acc;
    }
}

static size_t need_bytes(int CH2) {
    size_t s = 0;
    s += alignup((size_t)NN * 4);            // count
    s += alignup((size_t)(NN + 1) * 4);      // row_start
    s += alignup((size_t)NN * 4);            // cursor
    s += alignup(1024 * 4);                  // bsum
    s += alignup((size_t)NN * 4);            // dinv
    s += alignup((size_t)NE * 8);            // colval
    s += alignup((size_t)NN * C1 * 2);       // hw1
    s += alignup((size_t)NN * C1 * 2);       // h1
    s += alignup((size_t)NN * CH2 * 2);      // hw2 chunk
    s += alignup((size_t)NG * C2 * 4);       // pooled
    s += alignup((size_t)NG * 4);            // cnt
    return s;
}

template <int CH2>
static void run_pipeline(const float* x, const int* src, const int* dst, const int* bat,
                         const float* W1, const float* b1, const float* W2, const float* b2,
                         const float* fcw, const float* fcb, float* out,
                         char* ws, hipStream_t stream) {
    int* count   = (int*)ws;   ws += alignup((size_t)NN * 4);
    int* rs      = (int*)ws;   ws += alignup((size_t)(NN + 1) * 4);
    int* cursor  = (int*)ws;   ws += alignup((size_t)NN * 4);
    int* bsum    = (int*)ws;   ws += alignup(1024 * 4);
    float* dinv  = (float*)ws; ws += alignup((size_t)NN * 4);
    int2* colval = (int2*)ws;  ws += alignup((size_t)NE * 8);
    bf16* hw1    = (bf16*)ws;  ws += alignup((size_t)NN * C1 * 2);
    bf16* h1     = (bf16*)ws;  ws += alignup((size_t)NN * C1 * 2);
    bf16* hw2c   = (bf16*)ws;  ws += alignup((size_t)NN * CH2 * 2);
    float* pooled= (float*)ws; ws += alignup((size_t)NG * C2 * 4);
    float* cnt   = (float*)ws; ws += alignup((size_t)NG * 4);

    const int NB = (NN + 255) / 256;  // 782

    hipMemsetAsync(count, 0, (size_t)NN * 4, stream);
    hipMemsetAsync(pooled, 0, (size_t)NG * C2 * 4, stream);
    hipMemsetAsync(cnt, 0, (size_t)NG * 4, stream);

    // CSR build
    hist_kernel<<<(NE + 255) / 256, 256, 0, stream>>>(dst, count);
    dinv_kernel<<<NB, 256, 0, stream>>>(count, dinv);
    scan_block_kernel<<<NB, 256, 0, stream>>>(count, rs, bsum);
    scan_bsum_kernel<<<1, 1024, 0, stream>>>(bsum, NB);
    scan_add_kernel<<<NB, 256, 0, stream>>>(rs, bsum);
    copy_int_kernel<<<NB, 256, 0, stream>>>(rs, cursor);
    build_csr_kernel<<<(NE + 255) / 256, 256, 0, stream>>>(src, dst, dinv, cursor, colval);
    count_kernel<<<NB, 256, 0, stream>>>(bat, cnt);

    // layer 1 (full 64 ch)
    gemm1_kernel<<<NN / 4, 256, 0, stream>>>(x, W1, hw1);
    agg1_kernel<<<NN / 4, 256, 0, stream>>>(colval, rs, dinv, (const unsigned short*)hw1, b1, h1);

    // layer 2 (chunked over channels)
    for (int c0 = 0; c0 < C2; c0 += CH2) {
        gemm2_kernel<CH2><<<NN / (256 / CH2), 256, 0, stream>>>(h1, W2, c0, hw2c);
        agg2_kernel<CH2><<<NN / (256 / CH2), 256, 0, stream>>>(
            colval, rs, dinv, (const unsigned short*)hw2c, b2, c0, bat, pooled);
    }

    final_kernel<<<(NG * ODIM + 255) / 256, 256, 0, stream>>>(pooled, cnt, fcw, fcb, out);
}

extern "C" void kernel_launch(void* const* d_in, const int* in_sizes, int n_in,
                              void* d_out, int out_size, void* d_ws, size_t ws_size,
                              hipStream_t stream) {
    const float* x   = (const float*)d_in[0];
    const int*   ei  = (const int*)d_in[1];
    const int*   bat = (const int*)d_in[2];
    const float* W1  = (const float*)d_in[3];
    const float* b1  = (const float*)d_in[4];
    const float* W2  = (const float*)d_in[5];
    const float* b2  = (const float*)d_in[6];
    const float* fcw = (const float*)d_in[7];
    const float* fcb = (const float*)d_in[8];
    float* out = (float*)d_out;

    const int* src = ei;        // edge_index[0]
    const int* dst = ei + NE;   // edge_index[1]
    char* ws = (char*)d_ws;

    if (ws_size >= need_bytes(128))
        run_pipeline<128>(x, src, dst, bat, W1, b1, W2, b2, fcw, fcb, out, ws, stream);
    else if (ws_size >= need_bytes(64))
        run_pipeline<64>(x, src, dst, bat, W1, b1, W2, b2, fcw, fcb, out, ws, stream);
    else if (ws_size >= need_bytes(32))
        run_pipeline<32>(x, src, dst, bat, W1, b1, W2, b2, fcw, fcb, out, ws, stream);
    else
        run_pipeline<16>(x, src, dst, bat, W1, b1, W2, b2, fcw, fcb, out, ws, stream);
}

// Round 4
// 894.876 us; speedup vs baseline: 10.1789x; 1.5004x over previous
//
#include <hip/hip_runtime.h>
#include <hip/hip_bf16.h>

#define NN 200000
#define NE 3200000
#define NG 4096
#define INC 78
#define C1 64
#define C2 128
#define ODIM 128
#define KP1 96   // K of layer-1 GEMM padded to multiple of 32

using bf16 = __hip_bfloat16;
typedef __attribute__((ext_vector_type(8))) short bf16x8;
typedef __attribute__((ext_vector_type(4))) float f32x4;

static inline size_t alignup(size_t x) { return (x + 255) & ~size_t(255); }

__device__ __forceinline__ float bf2f(unsigned short u) {
    return __uint_as_float(((unsigned)u) << 16);
}
__device__ __forceinline__ unsigned short f2bf(float f) {
    __hip_bfloat16 h = __float2bfloat16(f);
    return *reinterpret_cast<unsigned short*>(&h);
}

// ---------------- CSR build ----------------
__global__ void hist_kernel(const int* __restrict__ dst, int* __restrict__ count) {
    int e = blockIdx.x * 256 + threadIdx.x;
    if (e < NE) atomicAdd(&count[dst[e]], 1);
}

__global__ void dinv_kernel(const int* __restrict__ count, float* __restrict__ dinv) {
    int n = blockIdx.x * 256 + threadIdx.x;
    if (n < NN) dinv[n] = rsqrtf((float)count[n] + 1.0f);
}

__global__ void scan_block_kernel(const int* __restrict__ in, int* __restrict__ out,
                                  int* __restrict__ bsum) {
    __shared__ int tmp[256];
    int tid = threadIdx.x, gid = blockIdx.x * 256 + tid;
    int v = (gid < NN) ? in[gid] : 0;
    tmp[tid] = v;
    __syncthreads();
    for (int off = 1; off < 256; off <<= 1) {
        int t = (tid >= off) ? tmp[tid - off] : 0;
        __syncthreads();
        tmp[tid] += t;
        __syncthreads();
    }
    if (gid < NN) out[gid] = tmp[tid] - v;
    if (tid == 255) bsum[blockIdx.x] = tmp[255];
}

__global__ void scan_bsum_kernel(int* __restrict__ bsum, int nb) {
    __shared__ int tmp[1024];
    int tid = threadIdx.x;
    int v = (tid < nb) ? bsum[tid] : 0;
    tmp[tid] = v;
    __syncthreads();
    for (int off = 1; off < 1024; off <<= 1) {
        int t = (tid >= off) ? tmp[tid - off] : 0;
        __syncthreads();
        tmp[tid] += t;
        __syncthreads();
    }
    if (tid < nb) bsum[tid] = tmp[tid] - v;
}

__global__ void scan_add_kernel(int* __restrict__ rs, const int* __restrict__ bsum) {
    int gid = blockIdx.x * 256 + threadIdx.x;
    if (gid < NN) rs[gid] += bsum[blockIdx.x];
    if (gid == 0) rs[NN] = NE;
}

__global__ void copy_int_kernel(const int* __restrict__ a, int* __restrict__ b) {
    int i = blockIdx.x * 256 + threadIdx.x;
    if (i < NN) b[i] = a[i];
}

__global__ void build_csr_kernel(const int* __restrict__ src, const int* __restrict__ dst,
                                 const float* __restrict__ dinv, int* __restrict__ cursor,
                                 int2* __restrict__ colval) {
    int e = blockIdx.x * 256 + threadIdx.x;
    if (e < NE) {
        int s = src[e], d = dst[e];
        int pos = atomicAdd(&cursor[d], 1);
        int2 cv;
        cv.x = s;
        cv.y = __float_as_int(dinv[s]);
        colval[pos] = cv;
    }
}

__global__ void count_kernel(const int* __restrict__ batch, float* __restrict__ cnt) {
    int n = blockIdx.x * 256 + threadIdx.x;
    if (n < NN) atomicAdd(&cnt[batch[n]], 1.0f);
}

// ---------------- weight / input conversion ----------------
// xb[n][k] = bf16(x[n][k]) for k<INC else 0, rows padded to KP1
__global__ void convx_kernel(const float* __restrict__ x, unsigned short* __restrict__ xb) {
    constexpr int G = KP1 / 8;
    int idx = blockIdx.x * 256 + threadIdx.x;
    if (idx >= NN * G) return;
    int n = idx / G, g = idx % G;
    union { bf16x8 v; unsigned short u[8]; } o;
    #pragma unroll
    for (int i = 0; i < 8; ++i) {
        int k = g * 8 + i;
        float f = (k < INC) ? x[(size_t)n * INC + k] : 0.f;
        o.u[i] = f2bf(f);
    }
    *reinterpret_cast<bf16x8*>(xb + (size_t)n * KP1 + g * 8) = o.v;
}

// Wt[c][k] = bf16(W[k][c]) (col-major, k padded to KP with zeros)
__global__ void convw_kernel(const float* __restrict__ W, unsigned short* __restrict__ Wt,
                             int N, int K, int KP) {
    int idx = blockIdx.x * 256 + threadIdx.x;
    if (idx >= N * KP) return;
    int c = idx / KP, k = idx % KP;
    float f = (k < K) ? W[k * N + c] : 0.f;
    Wt[idx] = f2bf(f);
}

// ---------------- MFMA GEMMs ----------------
// hw1 = bf16(xb @ W1)  M=NN K=KP1 N=64. Block: 4 waves, 64 rows; wave: 16 rows x 64 cols.
__global__ void gemm1_mfma(const unsigned short* __restrict__ xb,
                           const unsigned short* __restrict__ Wt1,  // [64][KP1]
                           unsigned short* __restrict__ hw1) {
    int wave = threadIdx.x >> 6, lane = threadIdx.x & 63;
    int r = lane & 15, kg = lane >> 4;
    int row0 = blockIdx.x * 64 + wave * 16;
    const unsigned short* arow = xb + (size_t)(row0 + r) * KP1 + kg * 8;
    bf16x8 a0 = *(const bf16x8*)(arow);
    bf16x8 a1 = *(const bf16x8*)(arow + 32);
    bf16x8 a2 = *(const bf16x8*)(arow + 64);
    #pragma unroll
    for (int nt = 0; nt < 4; ++nt) {
        const unsigned short* wrow = Wt1 + (size_t)(nt * 16 + r) * KP1 + kg * 8;
        bf16x8 b0 = *(const bf16x8*)(wrow);
        bf16x8 b1 = *(const bf16x8*)(wrow + 32);
        bf16x8 b2 = *(const bf16x8*)(wrow + 64);
        f32x4 acc = {0.f, 0.f, 0.f, 0.f};
        acc = __builtin_amdgcn_mfma_f32_16x16x32_bf16(a0, b0, acc, 0, 0, 0);
        acc = __builtin_amdgcn_mfma_f32_16x16x32_bf16(a1, b1, acc, 0, 0, 0);
        acc = __builtin_amdgcn_mfma_f32_16x16x32_bf16(a2, b2, acc, 0, 0, 0);
        unsigned short* cb = hw1 + (size_t)(row0 + kg * 4) * C1 + nt * 16 + r;
        #pragma unroll
        for (int i = 0; i < 4; ++i) cb[(size_t)i * C1] = f2bf(acc[i]);
    }
}

// hw2c = bf16(h1 @ W2[:, c0:c0+64])  M=NN K=64 N=64 per chunk.
__global__ void gemm2_mfma(const unsigned short* __restrict__ h1,
                           const unsigned short* __restrict__ Wt2c,  // [64 cols][64 k] (offset applied)
                           unsigned short* __restrict__ hw2c) {
    int wave = threadIdx.x >> 6, lane = threadIdx.x & 63;
    int r = lane & 15, kg = lane >> 4;
    int row0 = blockIdx.x * 64 + wave * 16;
    const unsigned short* arow = h1 + (size_t)(row0 + r) * C1 + kg * 8;
    bf16x8 a0 = *(const bf16x8*)(arow);
    bf16x8 a1 = *(const bf16x8*)(arow + 32);
    #pragma unroll
    for (int nt = 0; nt < 4; ++nt) {
        const unsigned short* wrow = Wt2c + (size_t)(nt * 16 + r) * C1 + kg * 8;
        bf16x8 b0 = *(const bf16x8*)(wrow);
        bf16x8 b1 = *(const bf16x8*)(wrow + 32);
        f32x4 acc = {0.f, 0.f, 0.f, 0.f};
        acc = __builtin_amdgcn_mfma_f32_16x16x32_bf16(a0, b0, acc, 0, 0, 0);
        acc = __builtin_amdgcn_mfma_f32_16x16x32_bf16(a1, b1, acc, 0, 0, 0);
        unsigned short* cb = hw2c + (size_t)(row0 + kg * 4) * 64 + nt * 16 + r;
        #pragma unroll
        for (int i = 0; i < 4; ++i) cb[(size_t)i * 64] = f2bf(acc[i]);
    }
}

// ---------------- aggregation (gather, no atomics) ----------------
template <int C>
__device__ __forceinline__ float agg_edges(const int2* __restrict__ cv, int start, int len,
                                           const unsigned short* __restrict__ hw, int c) {
    float acc = 0.f;
    int e = 0;
    for (; e + 4 <= len; e += 4) {
        int2 a = cv[start + e + 0];
        int2 b = cv[start + e + 1];
        int2 c2 = cv[start + e + 2];
        int2 d = cv[start + e + 3];
        float va = bf2f(hw[(size_t)a.x * C + c]);
        float vb = bf2f(hw[(size_t)b.x * C + c]);
        float vc = bf2f(hw[(size_t)c2.x * C + c]);
        float vd = bf2f(hw[(size_t)d.x * C + c]);
        acc += va * __int_as_float(a.y) + vb * __int_as_float(b.y) +
               vc * __int_as_float(c2.y) + vd * __int_as_float(d.y);
    }
    for (; e < len; ++e) {
        int2 a = cv[start + e];
        acc += bf2f(hw[(size_t)a.x * C + c]) * __int_as_float(a.y);
    }
    return acc;
}

__global__ void agg1_kernel(const int2* __restrict__ cv, const int* __restrict__ rs,
                            const float* __restrict__ dinv, const unsigned short* __restrict__ hw1,
                            const float* __restrict__ b1, bf16* __restrict__ h1) {
    int node = blockIdx.x * 4 + (threadIdx.x >> 6);
    if (node >= NN) return;
    int c = threadIdx.x & 63;
    int start = rs[node], len = rs[node + 1] - start;
    float acc = agg_edges<C1>(cv, start, len, hw1, c);
    float dn = dinv[node];
    acc = dn * (acc + bf2f(hw1[(size_t)node * C1 + c]) * dn);
    float h = fmaxf(acc + b1[c], 0.f);
    h1[(size_t)node * C1 + c] = __float2bfloat16(h);
}

__global__ void agg2_kernel(const int2* __restrict__ cv, const int* __restrict__ rs,
                            const float* __restrict__ dinv, const unsigned short* __restrict__ hw,
                            const float* __restrict__ b2, int c0, const int* __restrict__ batch,
                            float* __restrict__ pooled) {
    int node = blockIdx.x * 4 + (threadIdx.x >> 6);
    if (node >= NN) return;
    int j = threadIdx.x & 63;
    int start = rs[node], len = rs[node + 1] - start;
    float acc = agg_edges<64>(cv, start, len, hw, j);
    float dn = dinv[node];
    acc = dn * (acc + bf2f(hw[(size_t)node * 64 + j]) * dn);
    float v = fmaxf(acc + b2[c0 + j], 0.f);
    atomicAdd(&pooled[(size_t)batch[node] * C2 + c0 + j], v);
}

// ---------------- final FC ----------------
__global__ void final_kernel(const float* __restrict__ pooled, const float* __restrict__ cnt,
                             const float* __restrict__ fcw, const float* __restrict__ fcb,
                             float* __restrict__ out) {
    int idx = blockIdx.x * 256 + threadIdx.x;
    if (idx < NG * ODIM) {
        int g = idx >> 7;
        int o = idx & 127;
        float inv = 1.0f / fmaxf(cnt[g], 1.0f);
        float acc = fcb[o];
        const float* pr = pooled + (size_t)g * C2;
        #pragma unroll
        for (int k = 0; k < C2; ++k) acc += pr[k] * inv * fcw[k * ODIM + o];
        out[idx] = acc;
    }
}

extern "C" void kernel_launch(void* const* d_in, const int* in_sizes, int n_in,
                              void* d_out, int out_size, void* d_ws, size_t ws_size,
                              hipStream_t stream) {
    const float* x   = (const float*)d_in[0];
    const int*   ei  = (const int*)d_in[1];
    const int*   bat = (const int*)d_in[2];
    const float* W1  = (const float*)d_in[3];
    const float* b1  = (const float*)d_in[4];
    const float* W2  = (const float*)d_in[5];
    const float* b2  = (const float*)d_in[6];
    const float* fcw = (const float*)d_in[7];
    const float* fcb = (const float*)d_in[8];
    float* out = (float*)d_out;

    const int* src = ei;        // edge_index[0]
    const int* dst = ei + NE;   // edge_index[1]

    char* ws = (char*)d_ws;
    int* count   = (int*)ws;   ws += alignup((size_t)NN * 4);
    int* rs      = (int*)ws;   ws += alignup((size_t)(NN + 1) * 4);
    int* cursor  = (int*)ws;   ws += alignup((size_t)NN * 4);
    int* bsum    = (int*)ws;   ws += alignup(1024 * 4);
    float* dinv  = (float*)ws; ws += alignup((size_t)NN * 4);
    int2* colval = (int2*)ws;  ws += alignup((size_t)NE * 8);
    // hw1 region; reused as hw2 chunk after agg1 (hw1 dead then). 64ch both.
    unsigned short* hw1 = (unsigned short*)ws; ws += alignup((size_t)NN * C1 * 2);
    unsigned short* hw2c = hw1;
    // xb region (NN*KP1 bf16); reused as h1 (NN*64 bf16) after gemm1 (xb dead then).
    unsigned short* xb = (unsigned short*)ws; ws += alignup((size_t)NN * KP1 * 2);
    bf16* h1 = (bf16*)xb;
    unsigned short* Wt1 = (unsigned short*)ws; ws += alignup((size_t)C1 * KP1 * 2);
    unsigned short* Wt2 = (unsigned short*)ws; ws += alignup((size_t)C2 * C1 * 2);
    float* pooled = (float*)ws; ws += alignup((size_t)NG * C2 * 4);
    float* cnt    = (float*)ws; ws += alignup((size_t)NG * 4);

    const int NB = (NN + 255) / 256;  // 782

    hipMemsetAsync(count, 0, (size_t)NN * 4, stream);
    hipMemsetAsync(pooled, 0, (size_t)NG * C2 * 4, stream);
    hipMemsetAsync(cnt, 0, (size_t)NG * 4, stream);

    // CSR build + norm
    hist_kernel<<<(NE + 255) / 256, 256, 0, stream>>>(dst, count);
    dinv_kernel<<<NB, 256, 0, stream>>>(count, dinv);
    scan_block_kernel<<<NB, 256, 0, stream>>>(count, rs, bsum);
    scan_bsum_kernel<<<1, 1024, 0, stream>>>(bsum, NB);
    scan_add_kernel<<<NB, 256, 0, stream>>>(rs, bsum);
    copy_int_kernel<<<NB, 256, 0, stream>>>(rs, cursor);
    build_csr_kernel<<<(NE + 255) / 256, 256, 0, stream>>>(src, dst, dinv, cursor, colval);
    count_kernel<<<NB, 256, 0, stream>>>(bat, cnt);

    // input/weight conversions
    convx_kernel<<<(NN * (KP1 / 8) + 255) / 256, 256, 0, stream>>>(x, xb);
    convw_kernel<<<(C1 * KP1 + 255) / 256, 256, 0, stream>>>(W1, Wt1, C1, INC, KP1);
    convw_kernel<<<(C2 * C1 + 255) / 256, 256, 0, stream>>>(W2, Wt2, C2, C1, C1);

    // layer 1: MFMA GEMM + gather aggregate
    gemm1_mfma<<<NN / 64, 256, 0, stream>>>(xb, Wt1, hw1);
    agg1_kernel<<<NN / 4, 256, 0, stream>>>(colval, rs, dinv, hw1, b1, h1);

    // layer 2: two 64-col chunks
    for (int c0 = 0; c0 < C2; c0 += 64) {
        gemm2_mfma<<<NN / 64, 256, 0, stream>>>((const unsigned short*)h1,
                                                Wt2 + (size_t)c0 * C1, hw2c);
        agg2_kernel<<<NN / 4, 256, 0, stream>>>(colval, rs, dinv, hw2c, b2, c0, bat, pooled);
    }

    final_kernel<<<(NG * ODIM + 255) / 256, 256, 0, stream>>>(pooled, cnt, fcw, fcb, out);
}